// Round 3
// baseline (215.871 us; speedup 1.0000x reference)
//
#include <hip/hip_runtime.h>

#define DEV __device__ __forceinline__

typedef __bf16 bf16_t;
typedef bf16_t bf16x8 __attribute__((ext_vector_type(8)));
typedef float f32x4 __attribute__((ext_vector_type(4)));

static constexpr int VOCAB = 32000, DIM = 1024, BATCH = 64, SEQ = 512;
static constexpr int M_SC = BATCH * SEQ;  // 32768

DEV unsigned short f2bf(float f) {
  unsigned u = __builtin_bit_cast(unsigned, f);
  u += 0x7FFFu + ((u >> 16) & 1u);  // RNE, inputs are finite
  return (unsigned short)(u >> 16);
}

DEV float sigmf(float x) {
  x = fminf(fmaxf(x, -30.f), 30.f);
  return 1.0f / (1.0f + __expf(-x));
}

DEV float tanh_fast(float x) {
  x = fminf(fmaxf(x, -20.f), 20.f);
  float e = __expf(2.0f * x);
  return (e - 1.0f) / (e + 1.0f);
}

DEV void gload_lds16(const void* g, void* l) {
  __builtin_amdgcn_global_load_lds(
      (__attribute__((address_space(1))) void*)(g),
      (__attribute__((address_space(3))) void*)(l), 16, 0, 0);
}

// ---------------- prep: enc_y + W1 -> bf16, zero att accumulator ------------
__global__ void __launch_bounds__(256) k_prep(const float* __restrict__ enc,
                                              const float* __restrict__ w1,
                                              unsigned short* __restrict__ enc_b,
                                              unsigned short* __restrict__ w1_b,
                                              float* __restrict__ att_l) {
  int gid = blockIdx.x * 256 + threadIdx.x;
  if (gid < M_SC) att_l[gid] = 0.f;
  const int ENC4 = (M_SC * DIM) / 4;       // 8388608
  const int TOT4 = ENC4 + (DIM * DIM) / 4; // + 262144
  int stride = gridDim.x * 256;
  for (int i = gid; i < TOT4; i += stride) {
    float4 v;
    unsigned short* dst;
    if (i < ENC4) {
      v = ((const float4*)enc)[i];
      dst = enc_b + (size_t)i * 4;
    } else {
      v = ((const float4*)w1)[i - ENC4];
      dst = w1_b + (size_t)(i - ENC4) * 4;
    }
    ushort4 o;
    o.x = f2bf(v.x); o.y = f2bf(v.y); o.z = f2bf(v.z); o.w = f2bf(v.w);
    *(ushort4*)dst = o;
  }
}

// ---------------- embedding gather + bf16 copies of emb/h -------------------
__global__ void k_embed(const int* __restrict__ x, const float* __restrict__ Femb,
                        const float* __restrict__ h, float* __restrict__ emb_f,
                        unsigned short* __restrict__ eh_b, unsigned short* __restrict__ h_b) {
  int b = blockIdx.x;
  int tok = x[b];
  for (int d = threadIdx.x; d < DIM; d += blockDim.x) {
    float e = Femb[(size_t)tok * DIM + d];
    float hv = h[b * DIM + d];
    emb_f[b * DIM + d] = e;
    unsigned short eb = f2bf(e), hb = f2bf(hv);
    eh_b[b * 2 * DIM + d] = eb;
    eh_b[b * 2 * DIM + DIM + d] = hb;
    h_b[b * DIM + d] = hb;
  }
}

// ---------------- skinny GEMM v3: C[64 x N] = A(bf16) . W(f32,[*][1024])^T --
// N-tile 16/block, K-tile 128, 4 waves (wave w owns rows [w*16,w*16+16)).
// 2-phase double-buffered: A via gload_lds (pre-swizzled source), B reg-staged
// f32->bf16 with T14 split (load k+1 early, cvt+ds_write after MFMA of k).
// One __syncthreads per K-tile. LDS swizzle kills ds_read bank conflicts.
__global__ void __launch_bounds__(256) k_skinny(
    const unsigned short* __restrict__ A, int lda,
    const float* __restrict__ B1, const float* __restrict__ B2, int ksplit,
    const float* __restrict__ bias, float* __restrict__ C, int N, int K) {
  __shared__ unsigned short As[2][64 * 128];
  __shared__ unsigned short Bs[2][16 * 128];
  int t = threadIdx.x;
  int l = t & 63, w = t >> 6;
  int n0 = blockIdx.x * 16;
  f32x4 acc = {};
  int rx = (l & 7) << 3;  // read-side XOR (elems)

  // B staging geometry: 2 float4/thread
  int brow = 0, bc4 = 0;
  float4 vB[2];

  auto loadB = [&](int k0) {
    const float* Bsrc;
    int kk;
    if (k0 < ksplit) { Bsrc = B1; kk = k0; } else { Bsrc = B2; kk = k0 - ksplit; }
#pragma unroll
    for (int i = 0; i < 2; ++i) {
      int lin = i * 256 + t;
      int row = lin >> 5, c4 = (lin & 31) * 4;
      vB[i] = *(const float4*)(Bsrc + (size_t)(n0 + row) * 1024 + kk + c4);
    }
  };
  auto writeB = [&](int bufi) {
#pragma unroll
    for (int i = 0; i < 2; ++i) {
      int lin = i * 256 + t;
      int row = lin >> 5, c4 = (lin & 31) * 4;
      ushort4 o;
      o.x = f2bf(vB[i].x); o.y = f2bf(vB[i].y); o.z = f2bf(vB[i].z); o.w = f2bf(vB[i].w);
      *(ushort4*)&Bs[bufi][row * 128 + (c4 ^ ((row & 7) << 3))] = o;
    }
  };
  auto stageA = [&](int k0, int bufi) {
#pragma unroll
    for (int i = 0; i < 4; ++i) {
      int sbase = i * 256 + w * 64;       // wave-uniform 16B-slot base
      int s = sbase + l;
      int row = s >> 4;                   // 16 slots per 128-elem row
      int scol = ((s & 15) ^ (row & 7)) * 8;
      gload_lds16(A + (size_t)row * lda + k0 + scol, &As[bufi][sbase * 8]);
    }
  };

  // prologue: stage tile 0 into buf 0
  loadB(0);
  stageA(0, 0);
  writeB(0);
  __syncthreads();  // drains vmcnt+lgkm

  int nk = K / 128;
  int cur = 0;
  for (int kt = 0; kt < nk; ++kt) {
    bool pref = (kt + 1 < nk);
    if (pref) {
      loadB((kt + 1) * 128);             // global->reg, in flight
      stageA((kt + 1) * 128, cur ^ 1);   // global->LDS, in flight
    }
    // compute tile kt
#pragma unroll
    for (int kf = 0; kf < 4; ++kf) {
      int ko = kf * 32 + 8 * (l >> 4);
      int ar = w * 16 + (l & 15);
      bf16x8 af = *(const bf16x8*)&As[cur][ar * 128 + (ko ^ rx)];
      bf16x8 bf = *(const bf16x8*)&Bs[cur][(l & 15) * 128 + (ko ^ rx)];
      acc = __builtin_amdgcn_mfma_f32_16x16x32_bf16(af, bf, acc, 0, 0, 0);
    }
    if (pref) writeB(cur ^ 1);  // waits vB regs (auto vmcnt), writes next buf
    __syncthreads();            // drains gload_lds + ds_write for next iter
    cur ^= 1;
  }
  (void)brow; (void)bc4;

  int cn = n0 + (l & 15);
  float bv = bias ? bias[cn] : 0.f;
#pragma unroll
  for (int r = 0; r < 4; ++r) {
    int m = w * 16 + (l >> 4) * 4 + r;
    C[(size_t)m * N + cn] = acc[r] + bv;
  }
}

// ---------------- big fused score GEMM ---------------------------------------
// att_l[b*512+s] += sum_e tanh( (enc @ W1^T)[bs,e] + js[b,e] + W1_b[e] ) * Vw[e]
// M=32768, N=1024, K=1024; 128x128 tile, BK=64, 4 waves.
// 2-phase double-buffered gload_lds pipeline, one barrier per K-step.
// + XCD-aware block swizzle + LDS XOR swizzle (pre-swizzled source).
__global__ void __launch_bounds__(256) k_score(
    const unsigned short* __restrict__ encb, const unsigned short* __restrict__ w1mat,
    const float* __restrict__ js, const float* __restrict__ w1bias,
    const float* __restrict__ vw, float* __restrict__ att_l) {
  __shared__ unsigned short As[2][128 * 64];
  __shared__ unsigned short Bs[2][128 * 64];
  int t = threadIdx.x;
  int l = t & 63, w = t >> 6;
  int wr = w >> 1, wc = w & 1;
  // XCD swizzle: nwg=2048 (%8==0, bijective). XCD i gets m-tiles [i*32,(i+1)*32),
  // n fastest -> w1 L2-resident, A-tile reused by 8 consecutive blocks.
  int wg = blockIdx.x;
  int swz = (wg & 7) * 256 + (wg >> 3);
  int m0 = (swz >> 3) * 128;
  int n0 = (swz & 7) * 128;
  f32x4 acc[4][4] = {};

  int srow = l >> 3;                     // row within 8-row chunk
  int scol = ((l & 7) ^ (l >> 3)) * 8;   // pre-swizzled source col (elems)
  int rx = (l & 7) << 3;                 // read-side XOR (elems)

  const unsigned short* pa = encb + (size_t)m0 * DIM;
  const unsigned short* pb = w1mat + (size_t)n0 * DIM;

  auto stage = [&](int kt, int bufi) {
    int kbase = kt * 64;
#pragma unroll
    for (int i = 0; i < 4; ++i) {
      int chunk = i * 4 + w;          // 16 x 1KB chunks per tile
      int row = chunk * 8 + srow;     // 0..127
      gload_lds16(pa + (size_t)row * DIM + kbase + scol, &As[bufi][chunk * 512]);
      gload_lds16(pb + (size_t)row * DIM + kbase + scol, &Bs[bufi][chunk * 512]);
    }
  };

  stage(0, 0);
  __syncthreads();

  int cur = 0;
  for (int kt = 0; kt < 16; ++kt) {
    if (kt < 15) stage(kt + 1, cur ^ 1);  // prefetch in flight during compute
#pragma unroll
    for (int kh = 0; kh < 2; ++kh) {
      int ko = kh * 32 + 8 * (l >> 4);
      int kos = ko ^ rx;
      bf16x8 bfr[4], afr[4];
#pragma unroll
      for (int ni = 0; ni < 4; ++ni)
        bfr[ni] = *(const bf16x8*)&Bs[cur][(wc * 64 + ni * 16 + (l & 15)) * 64 + kos];
#pragma unroll
      for (int mi = 0; mi < 4; ++mi)
        afr[mi] = *(const bf16x8*)&As[cur][(wr * 64 + mi * 16 + (l & 15)) * 64 + kos];
#pragma unroll
      for (int mi = 0; mi < 4; ++mi)
#pragma unroll
        for (int ni = 0; ni < 4; ++ni)
          acc[mi][ni] = __builtin_amdgcn_mfma_f32_16x16x32_bf16(afr[mi], bfr[ni], acc[mi][ni], 0, 0, 0);
    }
    __syncthreads();  // drains prefetch vmcnt -> buf^1 ready
    cur ^= 1;
  }

  // fused epilogue
  int b = m0 >> 9;  // 128-row tile lies within one batch row block (512 rows)
  const float* jrow = js + b * DIM;
  float psum[4][4] = {};
#pragma unroll
  for (int ni = 0; ni < 4; ++ni) {
    int e = n0 + wc * 64 + ni * 16 + (l & 15);
    float jv = jrow[e] + w1bias[e];
    float vv = vw[e];
#pragma unroll
    for (int mi = 0; mi < 4; ++mi)
#pragma unroll
      for (int r = 0; r < 4; ++r)
        psum[mi][r] += tanh_fast(acc[mi][ni][r] + jv) * vv;
  }
#pragma unroll
  for (int mi = 0; mi < 4; ++mi)
#pragma unroll
    for (int r = 0; r < 4; ++r) {
      float s = psum[mi][r];
      s += __shfl_xor(s, 1);
      s += __shfl_xor(s, 2);
      s += __shfl_xor(s, 4);
      s += __shfl_xor(s, 8);
      if ((l & 15) == 0)
        atomicAdd(&att_l[m0 + wr * 64 + mi * 16 + (l >> 4) * 4 + r], s);
    }
}

// ---------------- softmax over s (512) per batch row -------------------------
__global__ void k_softmax(const float* __restrict__ att_l, float* __restrict__ att) {
  __shared__ float red[16];
  int b = blockIdx.x, t = threadIdx.x;  // 512 threads
  float v = att_l[b * SEQ + t];
  float m = v;
#pragma unroll
  for (int o = 32; o; o >>= 1) m = fmaxf(m, __shfl_xor(m, o));
  if ((t & 63) == 0) red[t >> 6] = m;
  __syncthreads();
  m = red[0];
#pragma unroll
  for (int i = 1; i < 8; ++i) m = fmaxf(m, red[i]);
  float e = __expf(v - m);
  float s = e;
#pragma unroll
  for (int o = 32; o; o >>= 1) s += __shfl_xor(s, o);
  __syncthreads();
  if ((t & 63) == 0) red[8 + (t >> 6)] = s;
  __syncthreads();
  s = 0.f;
#pragma unroll
  for (int i = 0; i < 8; ++i) s += red[8 + i];
  att[b * SEQ + t] = e / s;
}

// ---------------- LSTM pointwise + residual ----------------------------------
__global__ void k_lstm(const float* __restrict__ gates, const float* __restrict__ bih,
                       const float* __restrict__ bhh, const float* __restrict__ c,
                       const float* __restrict__ emb_f, float* __restrict__ out_h,
                       float* __restrict__ out_c, unsigned short* __restrict__ out_b) {
  int t = blockIdx.x * 256 + threadIdx.x;  // 65536
  int b = t >> 10, d = t & 1023;
  const float* g = gates + b * 4 * DIM;
  float ig = g[d] + bih[d] + bhh[d];
  float fg = g[DIM + d] + bih[DIM + d] + bhh[DIM + d];
  float gg = g[2 * DIM + d] + bih[2 * DIM + d] + bhh[2 * DIM + d];
  float og = g[3 * DIM + d] + bih[3 * DIM + d] + bhh[3 * DIM + d];
  float cn = sigmf(fg) * c[t] + sigmf(ig) * tanh_fast(gg);
  float hn = sigmf(og) * tanh_fast(cn);
  out_h[t] = hn;
  out_c[t] = cn;
  out_b[t] = f2bf(hn + emb_f[t]);  // residual, bf16 for logits GEMM
}

// -----------------------------------------------------------------------------
extern "C" void kernel_launch(void* const* d_in, const int* in_sizes, int n_in,
                              void* d_out, int out_size, void* d_ws, size_t ws_size,
                              hipStream_t stream) {
  const int* x = (const int*)d_in[0];
  const float* h = (const float*)d_in[1];
  const float* c = (const float*)d_in[2];
  const float* enc = (const float*)d_in[3];
  const float* Femb = (const float*)d_in[4];
  const float* W1w = (const float*)d_in[5];
  const float* W1b = (const float*)d_in[6];
  const float* W2w = (const float*)d_in[7];
  const float* W2b = (const float*)d_in[8];
  const float* Vw = (const float*)d_in[9];
  // d_in[10] = V_b: softmax-invariant, unused
  const float* Wih = (const float*)d_in[11];
  const float* Whh = (const float*)d_in[12];
  const float* bih = (const float*)d_in[13];
  const float* bhh = (const float*)d_in[14];
  const float* fcw = (const float*)d_in[15];
  const float* fcb = (const float*)d_in[16];

  float* out_logits = (float*)d_out;
  float* out_h = out_logits + (size_t)BATCH * VOCAB;
  float* out_c = out_h + BATCH * DIM;
  float* out_att = out_c + BATCH * DIM;

  char* p = (char*)d_ws;
  unsigned short* enc_b = (unsigned short*)p; p += (size_t)M_SC * DIM * 2;
  unsigned short* w1_b = (unsigned short*)p;  p += (size_t)DIM * DIM * 2;
  float* att_l = (float*)p;                   p += (size_t)M_SC * 4;
  float* js = (float*)p;                      p += (size_t)BATCH * DIM * 4;
  float* emb_f = (float*)p;                   p += (size_t)BATCH * DIM * 4;
  unsigned short* eh_b = (unsigned short*)p;  p += (size_t)BATCH * 2 * DIM * 2;
  unsigned short* h_b = (unsigned short*)p;   p += (size_t)BATCH * DIM * 2;
  float* gates = (float*)p;                   p += (size_t)BATCH * 4 * DIM * 4;
  unsigned short* out_b = (unsigned short*)p; p += (size_t)BATCH * DIM * 2;

  hipLaunchKernelGGL(k_prep, dim3(2048), dim3(256), 0, stream, enc, W1w, enc_b, w1_b, att_l);
  hipLaunchKernelGGL(k_embed, dim3(BATCH), dim3(256), 0, stream, x, Femb, h, emb_f, eh_b, h_b);
  // j_s = h @ W2^T + W2_b  -> [64][1024]
  hipLaunchKernelGGL(k_skinny, dim3(DIM / 16), dim3(256), 0, stream,
                     h_b, DIM, W2w, W2w, DIM, W2b, js, DIM, DIM);
  // fused attention scores -> att_l
  hipLaunchKernelGGL(k_score, dim3(2048), dim3(256), 0, stream,
                     enc_b, w1_b, js, W1b, Vw, att_l);
  hipLaunchKernelGGL(k_softmax, dim3(BATCH), dim3(SEQ), 0, stream, att_l, out_att);
  // gates = [emb|h] @ [W_ih|W_hh]^T  -> [64][4096] (biases added in k_lstm)
  hipLaunchKernelGGL(k_skinny, dim3(4 * DIM / 16), dim3(256), 0, stream,
                     eh_b, 2 * DIM, Wih, Whh, DIM, (const float*)nullptr, gates, 4 * DIM, 2 * DIM);
  hipLaunchKernelGGL(k_lstm, dim3(BATCH * DIM / 256), dim3(256), 0, stream,
                     gates, bih, bhh, c, emb_f, out_h, out_c, out_b);
  // logits = (h_new + emb) @ fc_w^T + fc_b
  hipLaunchKernelGGL(k_skinny, dim3(VOCAB / 16), dim3(256), 0, stream,
                     out_b, DIM, fcw, fcw, DIM, fcb, out_logits, VOCAB, DIM);
}

// Round 4
// 201.863 us; speedup vs baseline: 1.0694x; 1.0694x over previous
//
#include <hip/hip_runtime.h>

#define DEV __device__ __forceinline__

typedef __bf16 bf16_t;
typedef bf16_t bf16x8 __attribute__((ext_vector_type(8)));
typedef float f32x4 __attribute__((ext_vector_type(4)));

static constexpr int VOCAB = 32000, DIM = 1024, BATCH = 64, SEQ = 512;
static constexpr int M_SC = BATCH * SEQ;  // 32768

DEV unsigned short f2bf(float f) {
  unsigned u = __builtin_bit_cast(unsigned, f);
  u += 0x7FFFu + ((u >> 16) & 1u);  // RNE, inputs are finite
  return (unsigned short)(u >> 16);
}

DEV float sigmf(float x) {
  x = fminf(fmaxf(x, -30.f), 30.f);
  return 1.0f / (1.0f + __expf(-x));
}

DEV float tanh_fast(float x) {
  x = fminf(fmaxf(x, -20.f), 20.f);
  float e = __expf(2.0f * x);
  return (e - 1.0f) / (e + 1.0f);
}

DEV void gload_lds16(const void* g, void* l) {
  __builtin_amdgcn_global_load_lds(
      (__attribute__((address_space(1))) void*)(g),
      (__attribute__((address_space(3))) void*)(l), 16, 0, 0);
}

// ---------------- prep: enc_y + W1 -> bf16, zero att accumulator ------------
__global__ void __launch_bounds__(256) k_prep(const float* __restrict__ enc,
                                              const float* __restrict__ w1,
                                              unsigned short* __restrict__ enc_b,
                                              unsigned short* __restrict__ w1_b,
                                              float* __restrict__ att_l) {
  int gid = blockIdx.x * 256 + threadIdx.x;
  if (gid < M_SC) att_l[gid] = 0.f;
  const int ENC4 = (M_SC * DIM) / 4;       // 8388608
  const int TOT4 = ENC4 + (DIM * DIM) / 4; // + 262144
  int stride = gridDim.x * 256;
  for (int i = gid; i < TOT4; i += stride) {
    float4 v;
    unsigned short* dst;
    if (i < ENC4) {
      v = ((const float4*)enc)[i];
      dst = enc_b + (size_t)i * 4;
    } else {
      v = ((const float4*)w1)[i - ENC4];
      dst = w1_b + (size_t)(i - ENC4) * 4;
    }
    ushort4 o;
    o.x = f2bf(v.x); o.y = f2bf(v.y); o.z = f2bf(v.z); o.w = f2bf(v.w);
    *(ushort4*)dst = o;
  }
}

// ---------------- embedding gather + bf16 copies of emb/h -------------------
__global__ void k_embed(const int* __restrict__ x, const float* __restrict__ Femb,
                        const float* __restrict__ h, float* __restrict__ emb_f,
                        unsigned short* __restrict__ eh_b, unsigned short* __restrict__ h_b) {
  int b = blockIdx.x;
  int tok = x[b];
  for (int d = threadIdx.x; d < DIM; d += blockDim.x) {
    float e = Femb[(size_t)tok * DIM + d];
    float hv = h[b * DIM + d];
    emb_f[b * DIM + d] = e;
    unsigned short eb = f2bf(e), hb = f2bf(hv);
    eh_b[b * 2 * DIM + d] = eb;
    eh_b[b * 2 * DIM + DIM + d] = hb;
    h_b[b * DIM + d] = hb;
  }
}

// ---------------- skinny GEMM v4: C[64 x N] = A(bf16) . W(f32,[*][1024])^T --
// N-tile 16/block, K-tile 128, 4 waves. 2-phase double-buffer with COUNTED
// vmcnt (T4): raw s_barrier, vmcnt(6) lets the 6 prefetch loads (2 reg-B +
// 4 gload_lds-A) stay in flight across the barrier. lgkmcnt(0) before
// barrier B publishes the ds_writes of B.
__global__ void __launch_bounds__(256) k_skinny(
    const unsigned short* __restrict__ A, int lda,
    const float* __restrict__ B1, const float* __restrict__ B2, int ksplit,
    const float* __restrict__ bias, float* __restrict__ C, int N, int K) {
  __shared__ unsigned short As[2][64 * 128];
  __shared__ unsigned short Bs[2][16 * 128];
  int t = threadIdx.x;
  int l = t & 63, w = t >> 6;
  int n0 = blockIdx.x * 16;
  f32x4 acc = {};
  int rx = (l & 7) << 3;  // read-side XOR (elems)

  float4 vB[2];

  auto loadB = [&](int k0) {
    const float* Bsrc;
    int kk;
    if (k0 < ksplit) { Bsrc = B1; kk = k0; } else { Bsrc = B2; kk = k0 - ksplit; }
#pragma unroll
    for (int i = 0; i < 2; ++i) {
      int lin = i * 256 + t;
      int row = lin >> 5, c4 = (lin & 31) * 4;
      vB[i] = *(const float4*)(Bsrc + (size_t)(n0 + row) * 1024 + kk + c4);
    }
  };
  auto writeB = [&](int bufi) {
#pragma unroll
    for (int i = 0; i < 2; ++i) {
      int lin = i * 256 + t;
      int row = lin >> 5, c4 = (lin & 31) * 4;
      ushort4 o;
      o.x = f2bf(vB[i].x); o.y = f2bf(vB[i].y); o.z = f2bf(vB[i].z); o.w = f2bf(vB[i].w);
      *(ushort4*)&Bs[bufi][row * 128 + (c4 ^ ((row & 7) << 3))] = o;
    }
  };
  auto stageA = [&](int k0, int bufi) {
#pragma unroll
    for (int i = 0; i < 4; ++i) {
      int sbase = i * 256 + w * 64;       // wave-uniform 16B-slot base
      int s = sbase + l;
      int row = s >> 4;                   // 16 slots per 128-elem row
      int scol = ((s & 15) ^ (row & 7)) * 8;
      gload_lds16(A + (size_t)row * lda + k0 + scol, &As[bufi][sbase * 8]);
    }
  };
  auto compute = [&](int bufi) {
#pragma unroll
    for (int kf = 0; kf < 4; ++kf) {
      int ko = kf * 32 + 8 * (l >> 4);
      int ar = w * 16 + (l & 15);
      bf16x8 af = *(const bf16x8*)&As[bufi][ar * 128 + (ko ^ rx)];
      bf16x8 bf = *(const bf16x8*)&Bs[bufi][(l & 15) * 128 + (ko ^ rx)];
      acc = __builtin_amdgcn_mfma_f32_16x16x32_bf16(af, bf, acc, 0, 0, 0);
    }
  };

  // prologue: tile 0 into buf 0 (A loads may stay in flight; B published)
  loadB(0);
  stageA(0, 0);
  writeB(0);
  asm volatile("s_waitcnt lgkmcnt(0)" ::: "memory");

  int nk = K / 128;
  int cur = 0;
  for (int kt = 0; kt < nk - 1; ++kt) {
    loadB((kt + 1) * 128);             // 2 global->reg, in flight
    stageA((kt + 1) * 128, cur ^ 1);   // 4 global->LDS, in flight
    // allow the 6 just-issued loads outstanding; forces stageA(kt) landed.
    asm volatile("s_waitcnt vmcnt(6)\n\ts_barrier" ::: "memory");
    compute(cur);
    writeB(cur ^ 1);                   // compiler waits vB regs only
    asm volatile("s_waitcnt lgkmcnt(0)\n\ts_barrier" ::: "memory");
    cur ^= 1;
  }
  asm volatile("s_waitcnt vmcnt(0)\n\ts_barrier" ::: "memory");
  compute(cur);

  int cn = n0 + (l & 15);
  float bv = bias ? bias[cn] : 0.f;
#pragma unroll
  for (int r = 0; r < 4; ++r) {
    int m = w * 16 + (l >> 4) * 4 + r;
    C[(size_t)m * N + cn] = acc[r] + bv;
  }
}

// ---------------- big fused score GEMM ---------------------------------------
// att_l[b*512+s] += sum_e tanh( (enc @ W1^T)[bs,e] + js[b,e] + W1_b[e] ) * Vw[e]
// M=32768, N=1024, K=1024; 128x128 tile, BK=64, 4 waves.
// T4 counted-vmcnt pipeline: raw s_barrier, vmcnt(8) keeps next tile's 8
// gload_lds in flight across the barrier (hazard proof in journal):
//   RAW: after each wave's vmcnt(8)+barrier, ALL waves' stage(t) landed.
//   WAR: stage(t+1) writes buf read at iter t-1, drained before barrier B(t-1).
// + T5 setprio around MFMA cluster, XCD swizzle, LDS XOR swizzle.
__global__ void __launch_bounds__(256) k_score(
    const unsigned short* __restrict__ encb, const unsigned short* __restrict__ w1mat,
    const float* __restrict__ js, const float* __restrict__ w1bias,
    const float* __restrict__ vw, float* __restrict__ att_l) {
  __shared__ unsigned short As[2][128 * 64];
  __shared__ unsigned short Bs[2][128 * 64];
  int t = threadIdx.x;
  int l = t & 63, w = t >> 6;
  int wr = w >> 1, wc = w & 1;
  // XCD swizzle: nwg=2048 (%8==0, bijective). XCD i gets m-tiles [i*32,(i+1)*32),
  // n fastest -> w1 L2-resident, A-tile reused by 8 consecutive blocks.
  int wg = blockIdx.x;
  int swz = (wg & 7) * 256 + (wg >> 3);
  int m0 = (swz >> 3) * 128;
  int n0 = (swz & 7) * 128;
  f32x4 acc[4][4] = {};

  int srow = l >> 3;                     // row within 8-row chunk
  int scol = ((l & 7) ^ (l >> 3)) * 8;   // pre-swizzled source col (elems)
  int rx = (l & 7) << 3;                 // read-side XOR (elems)

  const unsigned short* pa = encb + (size_t)m0 * DIM;
  const unsigned short* pb = w1mat + (size_t)n0 * DIM;

  auto stage = [&](int kt, int bufi) {
    int kbase = kt * 64;
#pragma unroll
    for (int i = 0; i < 4; ++i) {
      int chunk = i * 4 + w;          // 16 x 1KB chunks per tile
      int row = chunk * 8 + srow;     // 0..127
      gload_lds16(pa + (size_t)row * DIM + kbase + scol, &As[bufi][chunk * 512]);
      gload_lds16(pb + (size_t)row * DIM + kbase + scol, &Bs[bufi][chunk * 512]);
    }
  };
  auto compute = [&](int bufi) {
#pragma unroll
    for (int kh = 0; kh < 2; ++kh) {
      int ko = kh * 32 + 8 * (l >> 4);
      int kos = ko ^ rx;
      bf16x8 bfr[4], afr[4];
#pragma unroll
      for (int ni = 0; ni < 4; ++ni)
        bfr[ni] = *(const bf16x8*)&Bs[bufi][(wc * 64 + ni * 16 + (l & 15)) * 64 + kos];
#pragma unroll
      for (int mi = 0; mi < 4; ++mi)
        afr[mi] = *(const bf16x8*)&As[bufi][(wr * 64 + mi * 16 + (l & 15)) * 64 + kos];
      __builtin_amdgcn_s_setprio(1);
#pragma unroll
      for (int mi = 0; mi < 4; ++mi)
#pragma unroll
        for (int ni = 0; ni < 4; ++ni)
          acc[mi][ni] = __builtin_amdgcn_mfma_f32_16x16x32_bf16(afr[mi], bfr[ni], acc[mi][ni], 0, 0, 0);
      __builtin_amdgcn_s_setprio(0);
    }
  };

  stage(0, 0);
  int cur = 0;
  for (int kt = 0; kt < 15; ++kt) {
    stage(kt + 1, cur ^ 1);   // 8 gload_lds, stay in flight across barrier
    asm volatile("s_waitcnt vmcnt(8)\n\ts_barrier" ::: "memory");
    compute(cur);
    asm volatile("s_barrier" ::: "memory");
    cur ^= 1;
  }
  asm volatile("s_waitcnt vmcnt(0)\n\ts_barrier" ::: "memory");
  compute(cur);

  // fused epilogue
  int b = m0 >> 9;  // 128-row tile lies within one batch row block (512 rows)
  const float* jrow = js + b * DIM;
  float psum[4][4] = {};
#pragma unroll
  for (int ni = 0; ni < 4; ++ni) {
    int e = n0 + wc * 64 + ni * 16 + (l & 15);
    float jv = jrow[e] + w1bias[e];
    float vv = vw[e];
#pragma unroll
    for (int mi = 0; mi < 4; ++mi)
#pragma unroll
      for (int r = 0; r < 4; ++r)
        psum[mi][r] += tanh_fast(acc[mi][ni][r] + jv) * vv;
  }
#pragma unroll
  for (int mi = 0; mi < 4; ++mi)
#pragma unroll
    for (int r = 0; r < 4; ++r) {
      float s = psum[mi][r];
      s += __shfl_xor(s, 1);
      s += __shfl_xor(s, 2);
      s += __shfl_xor(s, 4);
      s += __shfl_xor(s, 8);
      if ((l & 15) == 0)
        atomicAdd(&att_l[m0 + wr * 64 + mi * 16 + (l >> 4) * 4 + r], s);
    }
}

// ---------------- softmax over s (512) per batch row -------------------------
__global__ void k_softmax(const float* __restrict__ att_l, float* __restrict__ att) {
  __shared__ float red[16];
  int b = blockIdx.x, t = threadIdx.x;  // 512 threads
  float v = att_l[b * SEQ + t];
  float m = v;
#pragma unroll
  for (int o = 32; o; o >>= 1) m = fmaxf(m, __shfl_xor(m, o));
  if ((t & 63) == 0) red[t >> 6] = m;
  __syncthreads();
  m = red[0];
#pragma unroll
  for (int i = 1; i < 8; ++i) m = fmaxf(m, red[i]);
  float e = __expf(v - m);
  float s = e;
#pragma unroll
  for (int o = 32; o; o >>= 1) s += __shfl_xor(s, o);
  __syncthreads();
  if ((t & 63) == 0) red[8 + (t >> 6)] = s;
  __syncthreads();
  s = 0.f;
#pragma unroll
  for (int i = 0; i < 8; ++i) s += red[8 + i];
  att[b * SEQ + t] = e / s;
}

// ---------------- LSTM pointwise + residual ----------------------------------
__global__ void k_lstm(const float* __restrict__ gates, const float* __restrict__ bih,
                       const float* __restrict__ bhh, const float* __restrict__ c,
                       const float* __restrict__ emb_f, float* __restrict__ out_h,
                       float* __restrict__ out_c, unsigned short* __restrict__ out_b) {
  int t = blockIdx.x * 256 + threadIdx.x;  // 65536
  int b = t >> 10, d = t & 1023;
  const float* g = gates + b * 4 * DIM;
  float ig = g[d] + bih[d] + bhh[d];
  float fg = g[DIM + d] + bih[DIM + d] + bhh[DIM + d];
  float gg = g[2 * DIM + d] + bih[2 * DIM + d] + bhh[2 * DIM + d];
  float og = g[3 * DIM + d] + bih[3 * DIM + d] + bhh[3 * DIM + d];
  float cn = sigmf(fg) * c[t] + sigmf(ig) * tanh_fast(gg);
  float hn = sigmf(og) * tanh_fast(cn);
  out_h[t] = hn;
  out_c[t] = cn;
  out_b[t] = f2bf(hn + emb_f[t]);  // residual, bf16 for logits GEMM
}

// -----------------------------------------------------------------------------
extern "C" void kernel_launch(void* const* d_in, const int* in_sizes, int n_in,
                              void* d_out, int out_size, void* d_ws, size_t ws_size,
                              hipStream_t stream) {
  const int* x = (const int*)d_in[0];
  const float* h = (const float*)d_in[1];
  const float* c = (const float*)d_in[2];
  const float* enc = (const float*)d_in[3];
  const float* Femb = (const float*)d_in[4];
  const float* W1w = (const float*)d_in[5];
  const float* W1b = (const float*)d_in[6];
  const float* W2w = (const float*)d_in[7];
  const float* W2b = (const float*)d_in[8];
  const float* Vw = (const float*)d_in[9];
  // d_in[10] = V_b: softmax-invariant, unused
  const float* Wih = (const float*)d_in[11];
  const float* Whh = (const float*)d_in[12];
  const float* bih = (const float*)d_in[13];
  const float* bhh = (const float*)d_in[14];
  const float* fcw = (const float*)d_in[15];
  const float* fcb = (const float*)d_in[16];

  float* out_logits = (float*)d_out;
  float* out_h = out_logits + (size_t)BATCH * VOCAB;
  float* out_c = out_h + BATCH * DIM;
  float* out_att = out_c + BATCH * DIM;

  char* p = (char*)d_ws;
  unsigned short* enc_b = (unsigned short*)p; p += (size_t)M_SC * DIM * 2;
  unsigned short* w1_b = (unsigned short*)p;  p += (size_t)DIM * DIM * 2;
  float* att_l = (float*)p;                   p += (size_t)M_SC * 4;
  float* js = (float*)p;                      p += (size_t)BATCH * DIM * 4;
  float* emb_f = (float*)p;                   p += (size_t)BATCH * DIM * 4;
  unsigned short* eh_b = (unsigned short*)p;  p += (size_t)BATCH * 2 * DIM * 2;
  unsigned short* h_b = (unsigned short*)p;   p += (size_t)BATCH * DIM * 2;
  float* gates = (float*)p;                   p += (size_t)BATCH * 4 * DIM * 4;
  unsigned short* out_b = (unsigned short*)p; p += (size_t)BATCH * DIM * 2;

  hipLaunchKernelGGL(k_prep, dim3(2048), dim3(256), 0, stream, enc, W1w, enc_b, w1_b, att_l);
  hipLaunchKernelGGL(k_embed, dim3(BATCH), dim3(256), 0, stream, x, Femb, h, emb_f, eh_b, h_b);
  // j_s = h @ W2^T + W2_b  -> [64][1024]
  hipLaunchKernelGGL(k_skinny, dim3(DIM / 16), dim3(256), 0, stream,
                     h_b, DIM, W2w, W2w, DIM, W2b, js, DIM, DIM);
  // fused attention scores -> att_l
  hipLaunchKernelGGL(k_score, dim3(2048), dim3(256), 0, stream,
                     enc_b, w1_b, js, W1b, Vw, att_l);
  hipLaunchKernelGGL(k_softmax, dim3(BATCH), dim3(SEQ), 0, stream, att_l, out_att);
  // gates = [emb|h] @ [W_ih|W_hh]^T  -> [64][4096] (biases added in k_lstm)
  hipLaunchKernelGGL(k_skinny, dim3(4 * DIM / 16), dim3(256), 0, stream,
                     eh_b, 2 * DIM, Wih, Whh, DIM, (const float*)nullptr, gates, 4 * DIM, 2 * DIM);
  hipLaunchKernelGGL(k_lstm, dim3(BATCH * DIM / 256), dim3(256), 0, stream,
                     gates, bih, bhh, c, emb_f, out_h, out_c, out_b);
  // logits = (h_new + emb) @ fc_w^T + fc_b
  hipLaunchKernelGGL(k_skinny, dim3(VOCAB / 16), dim3(256), 0, stream,
                     out_b, DIM, fcw, fcw, DIM, fcb, out_logits, VOCAB, DIM);
}